// Round 1
// baseline (169.646 us; speedup 1.0000x reference)
//
#include <hip/hip_runtime.h>
#include <hip/hip_bf16.h>

// WordEmbed: out[token, :] = embedding[input_ids[token], :]
// ids: (2,2048) int32 -> 4096 tokens; embedding: (32000,1024) f32; out: (4096,1024) f32
// FEATURES = 1024 floats = 256 float4 per row -> one block of 256 threads per token.

__global__ __launch_bounds__(256) void WordEmbed_7971459302123_kernel(
    const int* __restrict__ ids,
    const float4* __restrict__ emb,   // [32000 * 256] float4
    float4* __restrict__ out)         // [4096 * 256] float4
{
    const int row = blockIdx.x;        // token index 0..4095
    const int t = threadIdx.x;         // 0..255 (float4 index within the row)
    const int id = ids[row];           // wave-uniform scalar load
    out[(size_t)row * 256 + t] = emb[(size_t)id * 256 + t];
}

extern "C" void kernel_launch(void* const* d_in, const int* in_sizes, int n_in,
                              void* d_out, int out_size, void* d_ws, size_t ws_size,
                              hipStream_t stream) {
    const int* ids = (const int*)d_in[0];           // 4096 int32
    const float4* emb = (const float4*)d_in[1];     // 32000*1024 f32
    float4* out = (float4*)d_out;                   // 4096*1024 f32

    const int n_tokens = in_sizes[0];               // 4096
    WordEmbed_7971459302123_kernel<<<n_tokens, 256, 0, stream>>>(ids, emb, out);
}

// Round 3
// 169.044 us; speedup vs baseline: 1.0036x; 1.0036x over previous
//
#include <hip/hip_runtime.h>
#include <hip/hip_bf16.h>

// WordEmbed: out[token, :] = embedding[input_ids[token], :]
// ids: (2,2048) int32 -> 4096 tokens; embedding: (32000,1024) f32; out: (4096,1024) f32
// 1024 floats = 256 float4 per row. 512 blocks x 256 threads, 8 tokens/block.
// Native clang vector type (not HIP_vector_type) so nontemporal builtins accept it.

typedef float vfloat4 __attribute__((ext_vector_type(4)));

#define TOKENS_PER_BLOCK 8

__global__ __launch_bounds__(256) void WordEmbed_7971459302123_kernel(
    const int* __restrict__ ids,
    const vfloat4* __restrict__ emb,   // [32000 * 256] vfloat4
    vfloat4* __restrict__ out)         // [4096 * 256] vfloat4
{
    const int t = threadIdx.x;                         // 0..255 (float4 idx in row)
    const int tok0 = blockIdx.x * TOKENS_PER_BLOCK;

    // Preload the block's ids once (wave-uniform scalar loads).
    int id[TOKENS_PER_BLOCK];
#pragma unroll
    for (int i = 0; i < TOKENS_PER_BLOCK; ++i)
        id[i] = ids[tok0 + i];

#pragma unroll
    for (int i = 0; i < TOKENS_PER_BLOCK; ++i) {
        vfloat4 v = emb[(size_t)id[i] * 256 + t];
        __builtin_nontemporal_store(v, &out[(size_t)(tok0 + i) * 256 + t]);
    }
}

extern "C" void kernel_launch(void* const* d_in, const int* in_sizes, int n_in,
                              void* d_out, int out_size, void* d_ws, size_t ws_size,
                              hipStream_t stream) {
    const int* ids = (const int*)d_in[0];            // 4096 int32
    const vfloat4* emb = (const vfloat4*)d_in[1];    // 32000*1024 f32
    vfloat4* out = (vfloat4*)d_out;                  // 4096*1024 f32

    const int n_tokens = in_sizes[0];                // 4096
    const int n_blocks = (n_tokens + TOKENS_PER_BLOCK - 1) / TOKENS_PER_BLOCK; // 512
    WordEmbed_7971459302123_kernel<<<n_blocks, 256, 0, stream>>>(ids, emb, out);
}